// Round 1
// baseline (167.914 us; speedup 1.0000x reference)
//
#include <hip/hip_runtime.h>

#define NN 128
#define TT 256
#define EE 6
#define DD 10
#define TE (TT*EE)          // 1536
#define C1 15               // input1 inner dim: 1+E+E+2

// Kernel 0: w[j*TE + t*E + e] = 1 / input1[j,t,7+e]^2
__global__ __launch_bounds__(256) void prep_w(const float* __restrict__ input1,
                                              float* __restrict__ w) {
    int idx = blockIdx.x * 256 + threadIdx.x;      // over N*T*E = 196608
    if (idx < NN * TE) {
        int f = idx % TE;
        int j = idx / TE;
        int t = f / EE, e = f % EE;
        float v = input1[(j * TT + t) * C1 + 1 + EE + e];
        w[idx] = 1.0f / (v * v);
    }
}

// Kernel 1: raw[i,j] = sum_{t,e} (yij[i,j,t,e]-yi[j,t,e])^2 * w[j,t,e]
// 256-thread blocks; each of the 4 waves owns one (i,j) tile independently.
// Per tile: 1536 floats = 384 float4 = 64 lanes x 6 float4. No LDS, no barrier.
__global__ __launch_bounds__(256) void pair_reduce(const float* __restrict__ yij,
                                                   const float* __restrict__ yi,
                                                   const float* __restrict__ w,
                                                   float* __restrict__ raw) {
    const int lane = threadIdx.x & 63;
    const int tile = blockIdx.x * 4 + (threadIdx.x >> 6);   // 0..16383 = i*128+j
    const int j    = tile & (NN - 1);

    const float4* __restrict__ a  = (const float4*)(yij + (size_t)tile * TE);
    const float4* __restrict__ m  = (const float4*)(yi  + (size_t)j * TE);
    const float4* __restrict__ wv = (const float4*)(w   + (size_t)j * TE);

    float s0 = 0.0f, s1 = 0.0f, s2 = 0.0f, s3 = 0.0f;
#pragma unroll
    for (int k = 0; k < 6; ++k) {
        const int f = lane + k * 64;
        float4 x  = a[f];
        float4 mm = m[f];
        float4 ww = wv[f];
        float d0 = x.x - mm.x; s0 += d0 * d0 * ww.x;
        float d1 = x.y - mm.y; s1 += d1 * d1 * ww.y;
        float d2 = x.z - mm.z; s2 += d2 * d2 * ww.z;
        float d3 = x.w - mm.w; s3 += d3 * d3 * ww.w;
    }
    float s = (s0 + s1) + (s2 + s3);
#pragma unroll
    for (int off = 32; off > 0; off >>= 1) s += __shfl_down(s, off);
    if (lane == 0) raw[tile] = s;
}

// Kernel 2: L = mean_{i,j} | S_ij - 0.5*(sec[i,j]+sec[j,i]) |
// Single 1024-thread block: no memset, no atomics. 16 pairs per thread.
__global__ __launch_bounds__(1024) void finalize(const float* __restrict__ raw,
                                                 const float* __restrict__ samples,
                                                 float* __restrict__ out) {
    __shared__ float smp[DD * NN];     // transposed: smp[d*NN + n], stride-1 reads
    for (int k = threadIdx.x; k < NN * DD; k += 1024) {
        int n = k / DD, d = k % DD;
        smp[d * NN + n] = samples[k];
    }
    __syncthreads();

    float v = 0.0f;
#pragma unroll
    for (int it = 0; it < (NN * NN) / 1024; ++it) {
        const int p = it * 1024 + threadIdx.x;   // 0..16383
        const int i = p >> 7, j = p & (NN - 1);
        float S = 0.0f;
#pragma unroll
        for (int d = 0; d < DD; ++d) {
            float dd = smp[d * NN + j] - smp[d * NN + i];
            S += dd * dd;
        }
        const float sec = (raw[p] + raw[(j << 7) | i]) * (0.5f / (TE * 10.0f));
        v += fabsf(S * (1.0f / DD) - sec);
    }

#pragma unroll
    for (int off = 32; off > 0; off >>= 1) v += __shfl_down(v, off);
    __shared__ float ls[16];
    if ((threadIdx.x & 63) == 0) ls[threadIdx.x >> 6] = v;
    __syncthreads();
    if (threadIdx.x == 0) {
        float t = 0.0f;
#pragma unroll
        for (int q = 0; q < 16; ++q) t += ls[q];
        *out = t * (1.0f / (NN * NN));
    }
}

extern "C" void kernel_launch(void* const* d_in, const int* in_sizes, int n_in,
                              void* d_out, int out_size, void* d_ws, size_t ws_size,
                              hipStream_t stream) {
    // inputs (setup_inputs order): merged, y_pred_i, y_pred_ij, input1, samples, labels
    const float* y_pred_i  = (const float*)d_in[1];
    const float* y_pred_ij = (const float*)d_in[2];
    const float* input1    = (const float*)d_in[3];
    const float* samples   = (const float*)d_in[4];
    float* out = (float*)d_out;

    // workspace layout: w (N*TE floats) | raw (N*N floats)
    float* w   = (float*)d_ws;
    float* raw = w + (size_t)NN * TE;

    prep_w<<<(NN * TE + 255) / 256, 256, 0, stream>>>(input1, w);
    pair_reduce<<<(NN * NN) / 4, 256, 0, stream>>>(y_pred_ij, y_pred_i, w, raw);
    finalize<<<1, 1024, 0, stream>>>(raw, samples, out);
}

// Round 2
// 160.503 us; speedup vs baseline: 1.0462x; 1.0462x over previous
//
#include <hip/hip_runtime.h>

#define NN 128
#define TT 256
#define EE 6
#define DD 10
#define TE (TT*EE)          // 1536
#define C1 15               // input1 inner dim: 1+E+E+2

// Kernel 0: w[j*TE + t*E + e] = 1 / input1[j,t,7+e]^2 ; also zeroes out[0]
__global__ __launch_bounds__(256) void prep_w(const float* __restrict__ input1,
                                              float* __restrict__ w,
                                              float* __restrict__ out) {
    if (blockIdx.x == 0 && threadIdx.x == 0) out[0] = 0.0f;   // replaces memset dispatch
    int idx = blockIdx.x * 256 + threadIdx.x;      // over N*T*E = 196608
    if (idx < NN * TE) {
        int f = idx % TE;
        int j = idx / TE;
        int t = f / EE, e = f % EE;
        float v = input1[(j * TT + t) * C1 + 1 + EE + e];
        w[idx] = 1.0f / (v * v);
    }
}

// Kernel 1: raw[i,j] = sum_{t,e} (yij[i,j,t,e]-yi[j,t,e])^2 * w[j,t,e]
// 256-thread blocks, 4 waves. Wave->tile map: tile = wave*4096 + bid, so all
// 4 waves of a block share the SAME j -> yi/w tiles (12 KB) are L1-resident
// after wave 0 touches them. Each wave streams its own contiguous 6 KB of yij.
__global__ __launch_bounds__(256) void pair_reduce(const float* __restrict__ yij,
                                                   const float* __restrict__ yi,
                                                   const float* __restrict__ w,
                                                   float* __restrict__ raw) {
    const int lane = threadIdx.x & 63;
    const int tile = (threadIdx.x >> 6) * (NN * NN / 4) + blockIdx.x; // i*128+j
    const int j    = tile & (NN - 1);

    const float4* __restrict__ a  = (const float4*)(yij + (size_t)tile * TE);
    const float4* __restrict__ m  = (const float4*)(yi  + (size_t)j * TE);
    const float4* __restrict__ wv = (const float4*)(w   + (size_t)j * TE);

    float s0 = 0.0f, s1 = 0.0f, s2 = 0.0f, s3 = 0.0f;
#pragma unroll
    for (int k = 0; k < 6; ++k) {
        const int f = lane + k * 64;
        float4 x  = a[f];
        float4 mm = m[f];
        float4 ww = wv[f];
        float d0 = x.x - mm.x; s0 += d0 * d0 * ww.x;
        float d1 = x.y - mm.y; s1 += d1 * d1 * ww.y;
        float d2 = x.z - mm.z; s2 += d2 * d2 * ww.z;
        float d3 = x.w - mm.w; s3 += d3 * d3 * ww.w;
    }
    float s = (s0 + s1) + (s2 + s3);
#pragma unroll
    for (int off = 32; off > 0; off >>= 1) s += __shfl_down(s, off);
    if (lane == 0) raw[tile] = s;
}

// Kernel 2: L = mean_{i,j} | S_ij - 0.5*(sec[i,j]+sec[j,i]) |
// 64 blocks x 256 threads; one scaled atomicAdd per block (out pre-zeroed by prep_w).
__global__ __launch_bounds__(256) void finalize(const float* __restrict__ raw,
                                                const float* __restrict__ samples,
                                                float* __restrict__ out) {
    __shared__ float smp[DD * NN];     // transposed: smp[d*NN + n], stride-1 reads
    for (int k = threadIdx.x; k < NN * DD; k += 256) {
        int n = k / DD, d = k % DD;
        smp[d * NN + n] = samples[k];
    }
    __syncthreads();

    const int p = blockIdx.x * 256 + threadIdx.x;   // 0..16383
    const int i = p >> 7, j = p & (NN - 1);

    float S = 0.0f;
#pragma unroll
    for (int d = 0; d < DD; ++d) {
        float dd = smp[d * NN + j] - smp[d * NN + i];
        S += dd * dd;
    }
    const float sec = (raw[p] + raw[(j << 7) | i]) * (0.5f / (TE * 10.0f));
    float v = fabsf(S * (1.0f / DD) - sec);

#pragma unroll
    for (int off = 32; off > 0; off >>= 1) v += __shfl_down(v, off);

    __shared__ float ls[4];
    const int tid = threadIdx.x;
    if ((tid & 63) == 0) ls[tid >> 6] = v;
    __syncthreads();
    if (tid == 0)
        atomicAdd(out, (ls[0] + ls[1] + ls[2] + ls[3]) * (1.0f / (NN * NN)));
}

extern "C" void kernel_launch(void* const* d_in, const int* in_sizes, int n_in,
                              void* d_out, int out_size, void* d_ws, size_t ws_size,
                              hipStream_t stream) {
    // inputs (setup_inputs order): merged, y_pred_i, y_pred_ij, input1, samples, labels
    const float* y_pred_i  = (const float*)d_in[1];
    const float* y_pred_ij = (const float*)d_in[2];
    const float* input1    = (const float*)d_in[3];
    const float* samples   = (const float*)d_in[4];
    float* out = (float*)d_out;

    // workspace layout: w (N*TE floats) | raw (N*N floats)
    float* w   = (float*)d_ws;
    float* raw = w + (size_t)NN * TE;

    prep_w<<<(NN * TE + 255) / 256, 256, 0, stream>>>(input1, w, out);
    pair_reduce<<<NN * NN / 4, 256, 0, stream>>>(y_pred_ij, y_pred_i, w, raw);
    finalize<<<64, 256, 0, stream>>>(raw, samples, out);
}

// Round 5
// 158.551 us; speedup vs baseline: 1.0591x; 1.0123x over previous
//
#include <hip/hip_runtime.h>

#define NN 128
#define TT 256
#define EE 6
#define DD 10
#define TE (TT*EE)          // 1536
#define C1 15               // input1 inner dim: 1+E+E+2

typedef float f32x4 __attribute__((ext_vector_type(4)));  // native vector: OK for nontemporal builtin

// Fused kernel: per block, compute w[j] into LDS once (all 4 waves share j),
// then raw[i,j] = sum_{t,e} (yij[i,j,t,e]-yi[j,t,e])^2 * w[j,t,e]
// tile = wave*4096 + bid  ->  same j for all 4 waves; yi/w reused 4x per block.
__global__ __launch_bounds__(256) void pair_all(const float* __restrict__ yij,
                                                const float* __restrict__ yi,
                                                const float* __restrict__ input1,
                                                float* __restrict__ raw,
                                                float* __restrict__ out) {
    const int bid = blockIdx.x;
    const int tid = threadIdx.x;
    const int j   = bid & (NN - 1);

    if (bid == 0 && tid == 0) out[0] = 0.0f;   // replaces memset; finalize runs after us

    __shared__ f32x4 w4[TE / 4];               // 384 float4 = 1536 w values
    float* wl = (float*)w4;
    // w[k] = 1 / input1[j, t, 7+e]^2, k = t*6+e. 6 values/thread, L2-resident reads.
    const float* __restrict__ i1 = input1 + (size_t)j * TT * C1 + 1 + EE;
    for (int k = tid; k < TE; k += 256) {
        const int t = k / EE, e = k - t * EE;
        const float v = i1[t * C1 + e];
        wl[k] = 1.0f / (v * v);
    }
    __syncthreads();

    const int lane = tid & 63;
    const int tile = (tid >> 6) * (NN * NN / 4) + bid;   // i*128+j, same j per block

    const f32x4* __restrict__ a = (const f32x4*)(yij + (size_t)tile * TE);
    const f32x4* __restrict__ m = (const f32x4*)(yi  + (size_t)j * TE);

    float s0 = 0.0f, s1 = 0.0f, s2 = 0.0f, s3 = 0.0f;
#pragma unroll
    for (int k = 0; k < 6; ++k) {
        const int f = lane + k * 64;
        f32x4 x  = __builtin_nontemporal_load(&a[f]);    // zero-reuse stream
        f32x4 mm = m[f];                                 // L1-cached, 4x reuse
        f32x4 ww = w4[f];                                // LDS
        float d0 = x.x - mm.x; s0 += d0 * d0 * ww.x;
        float d1 = x.y - mm.y; s1 += d1 * d1 * ww.y;
        float d2 = x.z - mm.z; s2 += d2 * d2 * ww.z;
        float d3 = x.w - mm.w; s3 += d3 * d3 * ww.w;
    }
    float s = (s0 + s1) + (s2 + s3);
#pragma unroll
    for (int off = 32; off > 0; off >>= 1) s += __shfl_down(s, off);
    if (lane == 0) raw[tile] = s;
}

// Kernel 2: L = mean_{i,j} | S_ij - 0.5*(sec[i,j]+sec[j,i]) |
// 64 blocks x 256 threads; one scaled atomicAdd per block (out pre-zeroed by pair_all).
__global__ __launch_bounds__(256) void finalize(const float* __restrict__ raw,
                                                const float* __restrict__ samples,
                                                float* __restrict__ out) {
    __shared__ float smp[DD * NN];     // transposed: smp[d*NN + n], stride-1 reads
    for (int k = threadIdx.x; k < NN * DD; k += 256) {
        int n = k / DD, d = k % DD;
        smp[d * NN + n] = samples[k];
    }
    __syncthreads();

    const int p = blockIdx.x * 256 + threadIdx.x;   // 0..16383
    const int i = p >> 7, j = p & (NN - 1);

    float S = 0.0f;
#pragma unroll
    for (int d = 0; d < DD; ++d) {
        float dd = smp[d * NN + j] - smp[d * NN + i];
        S += dd * dd;
    }
    const float sec = (raw[p] + raw[(j << 7) | i]) * (0.5f / (TE * 10.0f));
    float v = fabsf(S * (1.0f / DD) - sec);

#pragma unroll
    for (int off = 32; off > 0; off >>= 1) v += __shfl_down(v, off);

    __shared__ float ls[4];
    const int tid = threadIdx.x;
    if ((tid & 63) == 0) ls[tid >> 6] = v;
    __syncthreads();
    if (tid == 0)
        atomicAdd(out, (ls[0] + ls[1] + ls[2] + ls[3]) * (1.0f / (NN * NN)));
}

extern "C" void kernel_launch(void* const* d_in, const int* in_sizes, int n_in,
                              void* d_out, int out_size, void* d_ws, size_t ws_size,
                              hipStream_t stream) {
    // inputs (setup_inputs order): merged, y_pred_i, y_pred_ij, input1, samples, labels
    const float* y_pred_i  = (const float*)d_in[1];
    const float* y_pred_ij = (const float*)d_in[2];
    const float* input1    = (const float*)d_in[3];
    const float* samples   = (const float*)d_in[4];
    float* out = (float*)d_out;

    // workspace layout: raw (N*N floats) only
    float* raw = (float*)d_ws;

    pair_all<<<NN * NN / 4, 256, 0, stream>>>(y_pred_ij, y_pred_i, input1, raw, out);
    finalize<<<64, 256, 0, stream>>>(raw, samples, out);
}

// Round 6
// 155.546 us; speedup vs baseline: 1.0795x; 1.0193x over previous
//
#include <hip/hip_runtime.h>

#define NN 128
#define TT 256
#define EE 6
#define DD 10
#define TE (TT*EE)          // 1536
#define C1 15               // input1 inner dim: 1+E+E+2

typedef float f32x4 __attribute__((ext_vector_type(4)));

// Fused pair kernel: each wave owns 4 tiles (i0..i0+3, j) = 24 KB of yij stream.
// w[j] and yi[j] live in REGISTERS (24 w + 24 yi floats per lane) -> no LDS,
// no barrier, no block-level convoy. 1024 blocks x 4 waves; all waves of a
// block share j (L1 reuse), and all 8 blocks sharing j land on one XCD
// (128 % 8 == 0) so yi/input1 are single-L2-resident.
__global__ __launch_bounds__(256) void pair_all(const float* __restrict__ yij,
                                                const float* __restrict__ yi,
                                                const float* __restrict__ input1,
                                                float* __restrict__ raw,
                                                float* __restrict__ out) {
    const int bid  = blockIdx.x;            // 0..1023
    const int tid  = threadIdx.x;
    const int lane = tid & 63;
    const int wv   = tid >> 6;
    const int j    = bid & (NN - 1);
    const int i0   = (bid >> 7) * 16 + wv * 4;     // {0,4,...,124}

    if (bid == 0 && tid == 0) out[0] = 0.0f;       // finalize runs in a later dispatch

    // Register prologue: this lane's 24 slots are float indices 4*lane + c + 256*k.
    f32x4 wj[6], mj[6];
    const float* __restrict__ i1 = input1 + (size_t)j * TT * C1 + 1 + EE;  // [t*C1 + e]
#pragma unroll
    for (int k = 0; k < 6; ++k) {
        mj[k] = *(const f32x4*)(yi + (size_t)j * TE + 4 * lane + 256 * k);
        f32x4 t;
#pragma unroll
        for (int c = 0; c < 4; ++c) {
            const int idx = 4 * lane + c + 256 * k;        // < 1536
            const int tt  = idx / EE, e = idx - tt * EE;   // const-div -> magic mul
            const float v = i1[tt * C1 + e];
            t[c] = 1.0f / (v * v);
        }
        wj[k] = t;
    }

    // Stream 4 tiles of 6 KB each, non-temporal (zero reuse).
    float accs[4];
#pragma unroll
    for (int p = 0; p < 4; ++p) {
        const f32x4* __restrict__ a =
            (const f32x4*)(yij + ((size_t)(i0 + p) * NN + j) * TE);
        float s0 = 0.0f, s1 = 0.0f, s2 = 0.0f, s3 = 0.0f;
#pragma unroll
        for (int k = 0; k < 6; ++k) {
            f32x4 x = __builtin_nontemporal_load(&a[lane + 64 * k]);
            float d0 = x.x - mj[k].x; s0 += d0 * d0 * wj[k].x;
            float d1 = x.y - mj[k].y; s1 += d1 * d1 * wj[k].y;
            float d2 = x.z - mj[k].z; s2 += d2 * d2 * wj[k].z;
            float d3 = x.w - mj[k].w; s3 += d3 * d3 * wj[k].w;
        }
        accs[p] = (s0 + s1) + (s2 + s3);
    }

#pragma unroll
    for (int p = 0; p < 4; ++p) {
        float s = accs[p];
#pragma unroll
        for (int off = 32; off > 0; off >>= 1) s += __shfl_down(s, off);
        if (lane == 0) raw[(i0 + p) * NN + j] = s;
    }
}

// Kernel 2: L = mean_{i,j} | S_ij - 0.5*(sec[i,j]+sec[j,i]) |
// 64 blocks x 256 threads; one scaled atomicAdd per block (out pre-zeroed by pair_all).
__global__ __launch_bounds__(256) void finalize(const float* __restrict__ raw,
                                                const float* __restrict__ samples,
                                                float* __restrict__ out) {
    __shared__ float smp[DD * NN];     // transposed: smp[d*NN + n], stride-1 reads
    for (int k = threadIdx.x; k < NN * DD; k += 256) {
        int n = k / DD, d = k % DD;
        smp[d * NN + n] = samples[k];
    }
    __syncthreads();

    const int p = blockIdx.x * 256 + threadIdx.x;   // 0..16383
    const int i = p >> 7, j = p & (NN - 1);

    float S = 0.0f;
#pragma unroll
    for (int d = 0; d < DD; ++d) {
        float dd = smp[d * NN + j] - smp[d * NN + i];
        S += dd * dd;
    }
    const float sec = (raw[p] + raw[(j << 7) | i]) * (0.5f / (TE * 10.0f));
    float v = fabsf(S * (1.0f / DD) - sec);

#pragma unroll
    for (int off = 32; off > 0; off >>= 1) v += __shfl_down(v, off);

    __shared__ float ls[4];
    const int tid = threadIdx.x;
    if ((tid & 63) == 0) ls[tid >> 6] = v;
    __syncthreads();
    if (tid == 0)
        atomicAdd(out, (ls[0] + ls[1] + ls[2] + ls[3]) * (1.0f / (NN * NN)));
}

extern "C" void kernel_launch(void* const* d_in, const int* in_sizes, int n_in,
                              void* d_out, int out_size, void* d_ws, size_t ws_size,
                              hipStream_t stream) {
    // inputs (setup_inputs order): merged, y_pred_i, y_pred_ij, input1, samples, labels
    const float* y_pred_i  = (const float*)d_in[1];
    const float* y_pred_ij = (const float*)d_in[2];
    const float* input1    = (const float*)d_in[3];
    const float* samples   = (const float*)d_in[4];
    float* out = (float*)d_out;

    // workspace layout: raw (N*N floats) only
    float* raw = (float*)d_ws;

    pair_all<<<1024, 256, 0, stream>>>(y_pred_ij, y_pred_i, input1, raw, out);
    finalize<<<64, 256, 0, stream>>>(raw, samples, out);
}